// Round 1
// baseline (115.709 us; speedup 1.0000x reference)
//
#include <hip/hip_runtime.h>
#include <math.h>
#include <string.h>

#define N 12288
#define TILE 256
#define NSPLIT 16
#define JCHUNK (N / NSPLIT)   // 768

struct CMat { float c[6][6]; };

// ---------------- Kernel A: brute-force masked NN (argmin over d2) ----------
__global__ __launch_bounds__(256) void nn_kernel(
    const float* __restrict__ new_xyz,
    const float* __restrict__ gt_sdf,
    unsigned long long* __restrict__ packed)
{
    const int tid = threadIdx.x;
    const int i = blockIdx.x * TILE + tid;

    const float wx = new_xyz[3 * i + 0];
    const float wy = new_xyz[3 * i + 1];
    const float wz = new_xyz[3 * i + 2];
    const float sqi = wx * wx + wy * wy + wz * wz;

    __shared__ float4 tile[TILE];

    float bestd = INFINITY;
    int   bestj = 0;

    const int j0 = blockIdx.y * JCHUNK;

    for (int t = 0; t < JCHUNK; t += TILE) {
        const int j = j0 + t + tid;
        const float bx = new_xyz[3 * j + 0];
        const float by = new_xyz[3 * j + 1];
        const float bz = new_xyz[3 * j + 2];
        const float sqj = bx * bx + by * by + bz * bz;
        const bool ins = gt_sdf[j] < 1e-8f;
        tile[tid] = make_float4(bx, by, bz, ins ? sqj : 3e30f);
        __syncthreads();

        #pragma unroll 8
        for (int k = 0; k < TILE; ++k) {
            const float4 b = tile[k];
            const float d2 = (sqi + b.w) - 2.0f * (wx * b.x + wy * b.y + wz * b.z);
            const int jj = j0 + t + k;
            if (jj != i && d2 < bestd) { bestd = d2; bestj = jj; }
        }
        __syncthreads();
    }

    // monotone map float -> u32 (handles possible small negatives from cancellation)
    unsigned kb = __float_as_uint(bestd);
    kb = (kb >> 31) ? ~kb : (kb | 0x80000000u);
    const unsigned long long p =
        ((unsigned long long)kb << 32) | (unsigned long long)(unsigned)bestj;
    atomicMin(&packed[i], p);
}

// ---------------- Kernel B: strain quadratic form + reduction ---------------
__global__ __launch_bounds__(256) void loss_kernel(
    const float* __restrict__ new_xyz,
    const float* __restrict__ xyz,
    const float* __restrict__ gt_sdf,
    const unsigned long long* __restrict__ packed,
    double* __restrict__ sum_q2,
    unsigned int* __restrict__ n_valid,
    CMat C)
{
    const int tid = threadIdx.x;
    const int i = blockIdx.x * 256 + tid;

    const unsigned long long p = packed[i];
    const unsigned kb = (unsigned)(p >> 32);
    const unsigned bits = (kb & 0x80000000u) ? (kb ^ 0x80000000u) : ~kb;
    const float d2 = __uint_as_float(bits);
    const int nn = (int)(unsigned)(p & 0xffffffffu);

    const float nnd = sqrtf(fmaxf(d2, 0.0f));
    const bool inside = gt_sdf[i] < 1e-8f;
    const bool valid = inside && (nnd > 1e-8f);

    float q = 0.0f;
    if (valid) {
        const float wix = new_xyz[3 * i + 0], wiy = new_xyz[3 * i + 1], wiz = new_xyz[3 * i + 2];
        const float xix = xyz[3 * i + 0],     xiy = xyz[3 * i + 1],     xiz = xyz[3 * i + 2];
        const float wnx = new_xyz[3 * nn + 0], wny = new_xyz[3 * nn + 1], wnz = new_xyz[3 * nn + 2];
        const float xnx = xyz[3 * nn + 0],     xny = xyz[3 * nn + 1],     xnz = xyz[3 * nn + 2];

        // dm = motion[nn] - motion[i]
        const float du = (wnx - xnx) - (wix - xix);
        const float dv = (wny - xny) - (wiy - xiy);
        const float dw = (wnz - xnz) - (wiz - xiz);
        // dc = w[nn] - w[i] + 1e-8
        const float dx = wnx - wix + 1e-8f;
        const float dy = wny - wiy + 1e-8f;
        const float dz = wnz - wiz + 1e-8f;

        float et[6];
        et[0] = du / dx;
        et[1] = dv / dy;
        et[2] = dw / dz;
        et[3] = (du / dy + dv / dx) * 0.5f;
        et[4] = (du / dz + dw / dx) * 0.5f;
        et[5] = (dw / dy + dv / dz) * 0.5f;

        q = 0.0f;
        #pragma unroll
        for (int a = 0; a < 6; ++a) {
            float s = 0.0f;
            #pragma unroll
            for (int b = 0; b < 6; ++b) s += C.c[a][b] * et[b];
            q += et[a] * s;
        }
    }

    // reduce sum of q^2 (double) and count of valid across the block
    double q2 = (double)q * (double)q;
    #pragma unroll
    for (int off = 32; off > 0; off >>= 1)
        q2 += __shfl_down(q2, off, 64);

    const unsigned long long vm = __ballot(valid);
    const int lane = tid & 63;
    if (lane == 0) {
        atomicAdd(sum_q2, q2);
        atomicAdd(n_valid, (unsigned int)__popcll(vm));
    }
}

// ---------------- Kernel C: finalize ----------------------------------------
__global__ void final_kernel(const double* __restrict__ sum_q2,
                             const unsigned int* __restrict__ n_valid,
                             float* __restrict__ out)
{
    if (threadIdx.x == 0) {
        const double s = sqrt(*sum_q2);
        out[0] = (float)(s / (double)(*n_valid));
    }
}

// ---------------- Host: build C = inv(Ci) -----------------------------------
static void build_cmat(CMat* M)
{
    const double VP = 0.4, EP = 0.21;
    double A[6][12];
    memset(A, 0, sizeof(A));
    double Ci[6][6];
    memset(Ci, 0, sizeof(Ci));
    Ci[0][0] = 1.0 / EP; Ci[0][1] = -VP / EP; Ci[0][2] = -VP / EP;
    Ci[1][0] = -VP / EP; Ci[1][1] = 1.0 / EP; Ci[1][2] = -VP / EP;
    Ci[2][0] = -VP;      Ci[2][1] = -VP;      Ci[2][2] = 1.0 / EP;
    Ci[3][3] = 2.0 * (1.0 + VP) / EP;
    Ci[4][4] = Ci[3][3];
    Ci[5][5] = Ci[3][3];

    for (int i = 0; i < 6; ++i) {
        for (int j = 0; j < 6; ++j) A[i][j] = Ci[i][j];
        A[i][6 + i] = 1.0;
    }
    // Gauss-Jordan with partial pivoting
    for (int col = 0; col < 6; ++col) {
        int piv = col;
        for (int r = col + 1; r < 6; ++r)
            if (fabs(A[r][col]) > fabs(A[piv][col])) piv = r;
        if (piv != col)
            for (int c = 0; c < 12; ++c) { double t = A[col][c]; A[col][c] = A[piv][c]; A[piv][c] = t; }
        const double d = A[col][col];
        for (int c = 0; c < 12; ++c) A[col][c] /= d;
        for (int r = 0; r < 6; ++r) {
            if (r == col) continue;
            const double f = A[r][col];
            if (f == 0.0) continue;
            for (int c = 0; c < 12; ++c) A[r][c] -= f * A[col][c];
        }
    }
    for (int i = 0; i < 6; ++i)
        for (int j = 0; j < 6; ++j)
            M->c[i][j] = (float)A[i][6 + j];
}

extern "C" void kernel_launch(void* const* d_in, const int* in_sizes, int n_in,
                              void* d_out, int out_size, void* d_ws, size_t ws_size,
                              hipStream_t stream)
{
    const float* new_xyz = (const float*)d_in[0];
    const float* xyz     = (const float*)d_in[1];
    const float* gt_sdf  = (const float*)d_in[2];
    float* out = (float*)d_out;

    // workspace layout:
    //   [0,8):   double sum_q2
    //   [8,12):  unsigned n_valid
    //   [16, 16 + N*8): u64 packed best (d2key<<32 | idx)
    double* sum_q2 = (double*)d_ws;
    unsigned int* n_valid = (unsigned int*)((char*)d_ws + 8);
    unsigned long long* packed = (unsigned long long*)((char*)d_ws + 16);

    CMat C;
    build_cmat(&C);

    hipMemsetAsync(d_ws, 0, 16, stream);
    hipMemsetAsync((void*)packed, 0xFF, (size_t)N * 8, stream);

    nn_kernel<<<dim3(N / TILE, NSPLIT), TILE, 0, stream>>>(new_xyz, gt_sdf, packed);
    loss_kernel<<<N / 256, 256, 0, stream>>>(new_xyz, xyz, gt_sdf, packed,
                                             sum_q2, n_valid, C);
    final_kernel<<<1, 64, 0, stream>>>(sum_q2, n_valid, out);
}

// Round 2
// 94.892 us; speedup vs baseline: 1.2194x; 1.2194x over previous
//
#include <hip/hip_runtime.h>
#include <math.h>
#include <string.h>

#define N 12288
#define TILE 256          // j-points per block (one LDS tile, no tile loop)
#define IB 512            // i-points per block (2 per thread)
#define NBX (N / IB)      // 24
#define NBY (N / TILE)    // 48

typedef unsigned long long ull;

struct CMat { float c[6][6]; };

// ---------------------------------------------------------------------------
// Kernel A: brute-force masked NN. Block (bx,by) owns i in [bx*512, bx*512+512)
// (2 per thread) and j in [by*256, by*256+256) (one LDS tile). Writes packed
// (monotone-d2key<<32 | j) to a private slot packed[by*N + i] — no atomics.
// Inner-loop key is d2' = sqj_masked - 2*dot (sqi added back in the reducer).
// ---------------------------------------------------------------------------
template<int MODE>   // 0: check k!=tid for acc0; 1: for acc1; 2: no self check
__device__ __forceinline__ void nn_inner(
    const float4* __restrict__ tile, int tid,
    float wx0, float wy0, float wz0,
    float wx1, float wy1, float wz1,
    float& best0, int& bk0, float& best1, int& bk1)
{
    #pragma unroll 8
    for (int k = 0; k < TILE; ++k) {
        const float4 b = tile[k];
        const float d0 = fmaf(-2.0f, wx0 * b.x + wy0 * b.y + wz0 * b.z, b.w);
        const float d1 = fmaf(-2.0f, wx1 * b.x + wy1 * b.y + wz1 * b.z, b.w);
        bool ok0 = d0 < best0;
        bool ok1 = d1 < best1;
        if (MODE == 0) ok0 = ok0 && (k != tid);
        if (MODE == 1) ok1 = ok1 && (k != tid);
        if (ok0) { best0 = d0; bk0 = k; }
        if (ok1) { best1 = d1; bk1 = k; }
    }
}

__global__ __launch_bounds__(256) void nn_kernel(
    const float* __restrict__ new_xyz,
    const float* __restrict__ gt_sdf,
    ull* __restrict__ packed)
{
    const int tid = threadIdx.x;
    const int bx = blockIdx.x;
    const int by = blockIdx.y;

    const int i0 = bx * IB + tid;
    const int i1 = i0 + 256;

    const float wx0 = new_xyz[3 * i0 + 0];
    const float wy0 = new_xyz[3 * i0 + 1];
    const float wz0 = new_xyz[3 * i0 + 2];
    const float wx1 = new_xyz[3 * i1 + 0];
    const float wy1 = new_xyz[3 * i1 + 1];
    const float wz1 = new_xyz[3 * i1 + 2];

    __shared__ float4 tile[TILE];
    {
        const int j = by * TILE + tid;
        const float bxp = new_xyz[3 * j + 0];
        const float byp = new_xyz[3 * j + 1];
        const float bzp = new_xyz[3 * j + 2];
        const float sqj = bxp * bxp + byp * byp + bzp * bzp;
        const bool ins = gt_sdf[j] < 1e-8f;
        tile[tid] = make_float4(bxp, byp, bzp, ins ? sqj : 3e30f);
    }
    __syncthreads();

    float best0 = 3.0e38f, best1 = 3.0e38f;
    int bk0 = 0, bk1 = 0;

    if (by == 2 * bx)
        nn_inner<0>(tile, tid, wx0, wy0, wz0, wx1, wy1, wz1, best0, bk0, best1, bk1);
    else if (by == 2 * bx + 1)
        nn_inner<1>(tile, tid, wx0, wy0, wz0, wx1, wy1, wz1, best0, bk0, best1, bk1);
    else
        nn_inner<2>(tile, tid, wx0, wy0, wz0, wx1, wy1, wz1, best0, bk0, best1, bk1);

    const int jbase = by * TILE;

    unsigned kb0 = __float_as_uint(best0);
    kb0 = ((int)kb0 < 0) ? ~kb0 : (kb0 | 0x80000000u);
    packed[(size_t)by * N + i0] =
        ((ull)kb0 << 32) | (ull)(unsigned)(jbase + bk0);

    unsigned kb1 = __float_as_uint(best1);
    kb1 = ((int)kb1 < 0) ? ~kb1 : (kb1 | 0x80000000u);
    packed[(size_t)by * N + i1] =
        ((ull)kb1 << 32) | (ull)(unsigned)(jbase + bk1);
}

// ---------------------------------------------------------------------------
// Kernel B: per-i reduce over the 48 split slots, strain quadratic form,
// block-level reduction into per-block partials (no atomics, no memset).
// ---------------------------------------------------------------------------
__global__ __launch_bounds__(256) void loss_kernel(
    const float* __restrict__ new_xyz,
    const float* __restrict__ xyz,
    const float* __restrict__ gt_sdf,
    const ull* __restrict__ packed,
    double* __restrict__ partial_sum,
    unsigned int* __restrict__ partial_cnt,
    CMat C)
{
    const int tid = threadIdx.x;
    const int i = blockIdx.x * 256 + tid;

    ull best = ~0ull;
    #pragma unroll
    for (int s = 0; s < NBY; ++s) {
        const ull p = packed[(size_t)s * N + i];
        best = (p < best) ? p : best;
    }

    const unsigned kb = (unsigned)(best >> 32);
    const unsigned bits = (kb & 0x80000000u) ? (kb ^ 0x80000000u) : ~kb;
    const float key = __uint_as_float(bits);   // = min_j (sqj_masked - 2*dot)
    const int nn = (int)(unsigned)(best & 0xffffffffu);

    const float wix = new_xyz[3 * i + 0];
    const float wiy = new_xyz[3 * i + 1];
    const float wiz = new_xyz[3 * i + 2];
    const float sqi = wix * wix + wiy * wiy + wiz * wiz;

    const float d2 = sqi + key;
    const float nnd = sqrtf(fmaxf(d2, 0.0f));
    const bool inside = gt_sdf[i] < 1e-8f;
    const bool valid = inside && (nnd > 1e-8f);

    float q = 0.0f;
    if (valid) {
        const float xix = xyz[3 * i + 0], xiy = xyz[3 * i + 1], xiz = xyz[3 * i + 2];
        const float wnx = new_xyz[3 * nn + 0], wny = new_xyz[3 * nn + 1], wnz = new_xyz[3 * nn + 2];
        const float xnx = xyz[3 * nn + 0],     xny = xyz[3 * nn + 1],     xnz = xyz[3 * nn + 2];

        const float du = (wnx - xnx) - (wix - xix);
        const float dv = (wny - xny) - (wiy - xiy);
        const float dw = (wnz - xnz) - (wiz - xiz);
        const float dx = wnx - wix + 1e-8f;
        const float dy = wny - wiy + 1e-8f;
        const float dz = wnz - wiz + 1e-8f;

        float et[6];
        et[0] = du / dx;
        et[1] = dv / dy;
        et[2] = dw / dz;
        et[3] = (du / dy + dv / dx) * 0.5f;
        et[4] = (du / dz + dw / dx) * 0.5f;
        et[5] = (dw / dy + dv / dz) * 0.5f;

        #pragma unroll
        for (int a = 0; a < 6; ++a) {
            float s = 0.0f;
            #pragma unroll
            for (int b = 0; b < 6; ++b) s += C.c[a][b] * et[b];
            q += et[a] * s;
        }
    }

    // wave reduction (64 lanes)
    double q2 = (double)q * (double)q;
    #pragma unroll
    for (int off = 32; off > 0; off >>= 1)
        q2 += __shfl_down(q2, off, 64);
    const ull vm = __ballot(valid);
    const int lane = tid & 63;
    const int wid = tid >> 6;

    __shared__ double wsum[4];
    __shared__ unsigned wcnt[4];
    if (lane == 0) { wsum[wid] = q2; wcnt[wid] = (unsigned)__popcll(vm); }
    __syncthreads();
    if (tid == 0) {
        double s = wsum[0] + wsum[1] + wsum[2] + wsum[3];
        unsigned c = wcnt[0] + wcnt[1] + wcnt[2] + wcnt[3];
        partial_sum[blockIdx.x] = s;
        partial_cnt[blockIdx.x] = c;
    }
}

// ---------------------------------------------------------------------------
// Kernel C: finalize — sum 48 partials, out = sqrt(sum q^2) / n_valid
// ---------------------------------------------------------------------------
__global__ void final_kernel(const double* __restrict__ partial_sum,
                             const unsigned int* __restrict__ partial_cnt,
                             float* __restrict__ out)
{
    const int lane = threadIdx.x;   // 64 threads
    double s = (lane < NBY) ? partial_sum[lane] : 0.0;
    double c = (lane < NBY) ? (double)partial_cnt[lane] : 0.0;
    #pragma unroll
    for (int off = 32; off > 0; off >>= 1) {
        s += __shfl_down(s, off, 64);
        c += __shfl_down(c, off, 64);
    }
    if (lane == 0) out[0] = (float)(sqrt(s) / c);
}

// ---------------- Host: build C = inv(Ci) -----------------------------------
static void build_cmat(CMat* M)
{
    const double VP = 0.4, EP = 0.21;
    double A[6][12];
    memset(A, 0, sizeof(A));
    double Ci[6][6];
    memset(Ci, 0, sizeof(Ci));
    Ci[0][0] = 1.0 / EP; Ci[0][1] = -VP / EP; Ci[0][2] = -VP / EP;
    Ci[1][0] = -VP / EP; Ci[1][1] = 1.0 / EP; Ci[1][2] = -VP / EP;
    Ci[2][0] = -VP;      Ci[2][1] = -VP;      Ci[2][2] = 1.0 / EP;
    Ci[3][3] = 2.0 * (1.0 + VP) / EP;
    Ci[4][4] = Ci[3][3];
    Ci[5][5] = Ci[3][3];

    for (int i = 0; i < 6; ++i) {
        for (int j = 0; j < 6; ++j) A[i][j] = Ci[i][j];
        A[i][6 + i] = 1.0;
    }
    for (int col = 0; col < 6; ++col) {
        int piv = col;
        for (int r = col + 1; r < 6; ++r)
            if (fabs(A[r][col]) > fabs(A[piv][col])) piv = r;
        if (piv != col)
            for (int c = 0; c < 12; ++c) { double t = A[col][c]; A[col][c] = A[piv][c]; A[piv][c] = t; }
        const double d = A[col][col];
        for (int c = 0; c < 12; ++c) A[col][c] /= d;
        for (int r = 0; r < 6; ++r) {
            if (r == col) continue;
            const double f = A[r][col];
            if (f == 0.0) continue;
            for (int c = 0; c < 12; ++c) A[r][c] -= f * A[col][c];
        }
    }
    for (int i = 0; i < 6; ++i)
        for (int j = 0; j < 6; ++j)
            M->c[i][j] = (float)A[i][6 + j];
}

extern "C" void kernel_launch(void* const* d_in, const int* in_sizes, int n_in,
                              void* d_out, int out_size, void* d_ws, size_t ws_size,
                              hipStream_t stream)
{
    const float* new_xyz = (const float*)d_in[0];
    const float* xyz     = (const float*)d_in[1];
    const float* gt_sdf  = (const float*)d_in[2];
    float* out = (float*)d_out;

    // workspace layout (all fully written before read — no memset needed):
    //   [0, NBY*N*8)                 : packed u64 per (split, i)
    //   then 48 doubles (partial_sum), 48 uints (partial_cnt)
    const size_t packed_bytes = (size_t)NBY * N * sizeof(ull);
    ull* packed = (ull*)d_ws;
    double* partial_sum = (double*)((char*)d_ws + packed_bytes);
    unsigned int* partial_cnt = (unsigned int*)((char*)d_ws + packed_bytes + NBY * sizeof(double));

    CMat C;
    build_cmat(&C);

    nn_kernel<<<dim3(NBX, NBY), TILE, 0, stream>>>(new_xyz, gt_sdf, packed);
    loss_kernel<<<N / 256, 256, 0, stream>>>(new_xyz, xyz, gt_sdf, packed,
                                             partial_sum, partial_cnt, C);
    final_kernel<<<1, 64, 0, stream>>>(partial_sum, partial_cnt, out);
}